// Round 4
// baseline (250.650 us; speedup 1.0000x reference)
//
#include <hip/hip_runtime.h>

typedef short short8 __attribute__((ext_vector_type(8)));
typedef float float4v __attribute__((ext_vector_type(4)));
typedef __attribute__((address_space(1))) const unsigned int gu32;
typedef __attribute__((address_space(3))) unsigned int lu32;

__device__ __forceinline__ unsigned short f2bf(float f) {
  unsigned int u = __builtin_bit_cast(unsigned int, f);
  u += 0x7FFFu + ((u >> 16) & 1u);   // round-to-nearest-even
  return (unsigned short)(u >> 16);
}
__device__ __forceinline__ float bf2f(unsigned short s) {
  return __builtin_bit_cast(float, (unsigned int)s << 16);
}

template<int N> __device__ __forceinline__ void vmwait() {
  if constexpr (N == 0) asm volatile("s_waitcnt vmcnt(0)" ::: "memory");
  else if constexpr (N == 2) asm volatile("s_waitcnt vmcnt(2)" ::: "memory");
  else if constexpr (N == 3) asm volatile("s_waitcnt vmcnt(3)" ::: "memory");
  else if constexpr (N == 4) asm volatile("s_waitcnt vmcnt(4)" ::: "memory");
  else if constexpr (N == 6) asm volatile("s_waitcnt vmcnt(6)" ::: "memory");
  else if constexpr (N == 8) asm volatile("s_waitcnt vmcnt(8)" ::: "memory");
}

// prep_w: weight transposes + z conversion.
__global__ __launch_bounds__(256) void prep_w(
    const float* __restrict__ ww1, const float* __restrict__ ww2,
    const float* __restrict__ bw1, const float* __restrict__ bw2,
    const float* __restrict__ z,
    unsigned short* __restrict__ w1T, unsigned short* __restrict__ w2T,
    unsigned short* __restrict__ b1T, unsigned short* __restrict__ b2T,
    unsigned short* __restrict__ zb)
{
  int i = blockIdx.x * 256 + threadIdx.x;
  if (i < 131072) {
    int n = i & 511, k = i >> 9;
    w1T[n * 256 + k] = f2bf(ww1[i]);
  } else if (i < 655360) {
    int j = i - 131072; int n = j & 511, k = j >> 9;
    w2T[n * 1024 + k] = f2bf(ww2[j]);
  } else if (i < 786432) {
    int j = i - 655360; int n = j & 511, k = j >> 9;
    b1T[n * 256 + k] = f2bf(bw1[j]);
  } else if (i < 1310720) {
    int j = i - 786432; int n = j & 511, k = j >> 9;
    b2T[n * 1024 + k] = f2bf(bw2[j]);
  } else {
    int j = i - 1310720;
    zb[j] = f2bf(z[j]);
  }
}

// Unified GEMM core, glds(16B) staging, XOR-swizzled unpadded LDS.
// C[r,n] = act(biasv[n] + sum_k Ae[base(r)+kOff+k] * Bt[((n)&bRowMask)*Ktot + bOffB + kOff + k])
// base(r) = (r + (r/RPB)*EXTRA) * BSCALE;  Ae = (nHalf && n0>=nHalf) ? A2 : A.
// SPLITK: bz picks k-chunk; partial -> outp/outp2 (bf16).
// DBUF: 3-region counted-vmcnt pipeline (T4): depth-2 prefetch, raw s_barrier,
//   s_waitcnt vmcnt(AI+BI) (= one stage's glds stays in flight across the
//   barrier). Loads never drained to 0 in the main loop.
// !DBUF: BK=32*NH, stage-all -> barrier -> compute-all (1-phase).
// TRANS: out[bb*outBatchStride + (n0+f)*outLd + t_local] (bf16 via 2-pass LDS repack).
// ROWPACK: row-major bf16 store via LDS repack (stride BN+8), 2-pass when BM>64.
template<int BM, int BN, bool RELU, bool OBF16, bool TRANS, bool SPLITK, int NH,
         bool ROWPACK, bool DBUF>
__device__ __forceinline__ void gemm_core(
    int bx, int by, int bz, int nzTot, unsigned short* smem,
    const unsigned short* __restrict__ A,
    const unsigned short* __restrict__ A2,
    const unsigned short* __restrict__ Bt,
    const float* __restrict__ biasv,
    void* __restrict__ outp,
    void* __restrict__ outp2,
    int M, int Kchunk, int RPB, int EXTRA, int BSCALE,
    int nHalf, int bRowMask,
    long long bStrideB, long long outBatchStride, int outLd)
{
  constexpr int WM = BM / 2, WN = BN / 2;
  constexpr int NI = WM / 16, NJ = WN / 16;
  constexpr int AI = BM / 64;                 // glds instrs per wave per 32-chunk
  constexpr int BI = BN / 64;
  constexpr int SA1 = BM * 32, SB1 = BN * 32; // one 32-chunk region (shorts)
  unsigned short* sB0 = smem + NH * SA1;

  const int tid  = threadIdx.x;
  const int lane = tid & 63;
  const int wave = tid >> 6;
  const int wm = wave >> 1, wn = wave & 1;
  const int lr = lane & 15, quad = lane >> 4;

  const int r0 = bx * BM;
  const int n0 = by * BN;
  const int bb = r0 / RPB;
  const int Ktot = SPLITK ? Kchunk * nzTot : Kchunk;
  const int kOff = SPLITK ? bz * Kchunk : 0;
  const long long bOffB = (long long)bb * bStrideB;
  const unsigned short* Ae = (nHalf && n0 >= nHalf) ? A2 : A;

  const int srow = lane >> 2;
  const int sg = (lane & 3) ^ (srow & 3);     // XOR swizzle on fetch side
  const unsigned short* gA[AI];
#pragma unroll
  for (int c = 0; c < AI; ++c) {
    int instr = c * 4 + wave;
    int row = instr * 16 + srow;
    int r = r0 + row; if (r > M - 1) r = M - 1;          // clamp partial tiles
    gA[c] = Ae + ((long long)r + (long long)(r / RPB) * EXTRA) * BSCALE + kOff + sg * 8;
  }
  const unsigned short* gB[BI];
#pragma unroll
  for (int c = 0; c < BI; ++c) {
    int instr = c * 4 + wave;
    int row = instr * 16 + srow;
    gB[c] = Bt + (long long)((n0 + row) & bRowMask) * Ktot + bOffB + kOff + sg * 8;
  }

  int aoff[NI], boff[NJ];
#pragma unroll
  for (int i = 0; i < NI; ++i) {
    int rr = wm * WM + i * 16 + lr;
    aoff[i] = rr * 32 + ((quad ^ (rr & 3)) * 8);
  }
#pragma unroll
  for (int j = 0; j < NJ; ++j) {
    int rr = wn * WN + j * 16 + lr;
    boff[j] = rr * 32 + ((quad ^ (rr & 3)) * 8);
  }

  float4v acc[NI][NJ];
  const float4v z4 = {0.f, 0.f, 0.f, 0.f};
#pragma unroll
  for (int i = 0; i < NI; ++i)
#pragma unroll
    for (int j = 0; j < NJ; ++j) acc[i][j] = z4;

  if (DBUF) {
    // 3-region pipeline: region m holds one 32-chunk (A at +0, B at +SA1).
    constexpr int RS = SA1 + SB1;
    const int NT = Kchunk >> 5;
    auto stg = [&](int t, int m) {
      unsigned short* rb = smem + m * RS;
      int kk = t * 32;
#pragma unroll
      for (int c = 0; c < AI; ++c)
        __builtin_amdgcn_global_load_lds((gu32*)(gA[c] + kk),
                                         (lu32*)(rb + (c * 4 + wave) * 512), 16, 0, 0);
#pragma unroll
      for (int c = 0; c < BI; ++c)
        __builtin_amdgcn_global_load_lds((gu32*)(gB[c] + kk),
                                         (lu32*)(rb + SA1 + (c * 4 + wave) * 512), 16, 0, 0);
    };
    stg(0, 0); stg(1, 1);
    int m = 0;
    for (int t = 0; t < NT; ++t) {
      if (t + 1 < NT) vmwait<AI + BI>();
      else            vmwait<0>();
      __builtin_amdgcn_s_barrier();
      __builtin_amdgcn_sched_barrier(0);     // no ds_read may hoist above barrier
      int m2 = m + 2; if (m2 >= 3) m2 -= 3;
      if (t + 2 < NT) stg(t + 2, m2);
      const unsigned short* rb = smem + m * RS;
      short8 af[NI], bfr[NJ];
#pragma unroll
      for (int i = 0; i < NI; ++i) af[i] = *(const short8*)(rb + aoff[i]);
#pragma unroll
      for (int j = 0; j < NJ; ++j) bfr[j] = *(const short8*)(rb + SA1 + boff[j]);
#pragma unroll
      for (int i = 0; i < NI; ++i)
#pragma unroll
        for (int j = 0; j < NJ; ++j)
          acc[i][j] = __builtin_amdgcn_mfma_f32_16x16x32_bf16(af[i], bfr[j], acc[i][j], 0, 0, 0);
      if (++m == 3) m = 0;
    }
    __syncthreads();                         // all reads done before epilogue reuses LDS
  } else {
    for (int k0 = 0; k0 < Kchunk; k0 += 32 * NH) {
#pragma unroll
      for (int h = 0; h < NH; ++h) {
#pragma unroll
        for (int c = 0; c < AI; ++c)
          __builtin_amdgcn_global_load_lds((gu32*)(gA[c] + k0 + h * 32),
                                           (lu32*)(smem + (c * 4 + wave) * 512 + h * SA1), 16, 0, 0);
#pragma unroll
        for (int c = 0; c < BI; ++c)
          __builtin_amdgcn_global_load_lds((gu32*)(gB[c] + k0 + h * 32),
                                           (lu32*)(sB0 + (c * 4 + wave) * 512 + h * SB1), 16, 0, 0);
      }
      __syncthreads();
#pragma unroll
      for (int h = 0; h < NH; ++h) {
        short8 af[NI], bfr[NJ];
#pragma unroll
        for (int i = 0; i < NI; ++i) af[i] = *(const short8*)(smem + h * SA1 + aoff[i]);
#pragma unroll
        for (int j = 0; j < NJ; ++j) bfr[j] = *(const short8*)(sB0 + h * SB1 + boff[j]);
#pragma unroll
        for (int i = 0; i < NI; ++i)
#pragma unroll
          for (int j = 0; j < NJ; ++j)
            acc[i][j] = __builtin_amdgcn_mfma_f32_16x16x32_bf16(af[i], bfr[j], acc[i][j], 0, 0, 0);
      }
      __syncthreads();
    }
  }

  if (TRANS) {
    // 2-pass repack: pass p handles f-rows [p*WN, p*WN+WN) in a [WN][BM+8] buffer.
    unsigned short* Ts = smem;
    const int t0l = r0 - bb * RPB;
#pragma unroll
    for (int p = 0; p < 2; ++p) {
      if (wn == p) {
#pragma unroll
        for (int j = 0; j < NJ; ++j) {
          int frl = j * 16 + lr;                     // local f row in [0,WN)
          float bv = biasv[n0 + p * WN + frl];
#pragma unroll
          for (int i = 0; i < NI; ++i) {
            int tr = wm * WM + i * 16 + quad * 4;
            unsigned long long pk = 0;
#pragma unroll
            for (int g = 0; g < 4; ++g) {
              float vv = acc[i][j][g] + bv;
              if (RELU) vv = fmaxf(vv, 0.f);
              pk |= (unsigned long long)f2bf(vv) << (16 * g);
            }
            *(unsigned long long*)(Ts + frl * (BM + 8) + tr) = pk;
          }
        }
      }
      __syncthreads();
      // 256 threads store WN=64 rows x BM elements: 4 threads/row, BM/4 elems each
      int frl = tid >> 2, sgg = tid & 3;
      unsigned short* dst = (unsigned short*)outp + (long long)bb * outBatchStride
                          + (long long)(n0 + p * WN + frl) * outLd + t0l + sgg * (BM / 4);
      const unsigned short* srcp = Ts + frl * (BM + 8) + sgg * (BM / 4);
#pragma unroll
      for (int u = 0; u < BM / 32; ++u)
        *(uint4*)(dst + u * 8) = *(const uint4*)(srcp + u * 8);
      __syncthreads();
    }
  } else if (ROWPACK) {
    // row-major bf16 store via LDS repack (stride BN+8) + dwordx4.
    // 2-pass over row-halves when BM>64 so the buffer fits under the stage LDS.
    constexpr int P  = (BM > 64) ? 2 : 1;
    constexpr int RP = BM / P;                // rows per pass
    constexpr int BNP = BN + 8;
    constexpr int TPR = 256 / RP;             // threads per output row
    constexpr int EPT = BN / TPR;             // elements per thread
    void* op = (SPLITK && bz) ? outp2 : outp;
    unsigned short* R = smem;
#pragma unroll
    for (int p = 0; p < P; ++p) {
      if (P == 1 || wm == p) {
#pragma unroll
        for (int j = 0; j < NJ; ++j) {
          int cc = wn * WN + j * 16 + lr;
#pragma unroll
          for (int i = 0; i < NI; ++i) {
            int rl = (P == 1 ? wm * WM : 0) + i * 16 + quad * 4;
#pragma unroll
            for (int g = 0; g < 4; ++g)
              R[(rl + g) * BNP + cc] = f2bf(acc[i][j][g]);
          }
        }
      }
      __syncthreads();
      int rloc = tid / TPR, part = tid % TPR;
      unsigned short* dstp = (unsigned short*)op
                           + (long long)(r0 + p * RP + rloc) * outLd + n0 + part * EPT;
      const unsigned short* srcp = R + rloc * BNP + part * EPT;
#pragma unroll
      for (int u = 0; u < EPT / 8; ++u)
        *(uint4*)(dstp + u * 8) = *(const uint4*)(srcp + u * 8);
      if (p + 1 < P) __syncthreads();
    }
  } else {
    void* op = (SPLITK && bz) ? outp2 : outp;
#pragma unroll
    for (int j = 0; j < NJ; ++j) {
      int n_g = n0 + wn * WN + j * 16 + lr;
      float bv = biasv ? biasv[n_g] : 0.f;
#pragma unroll
      for (int i = 0; i < NI; ++i) {
        int r_base = r0 + wm * WM + i * 16 + quad * 4;
#pragma unroll
        for (int g = 0; g < 4; ++g) {
          int r_g = r_base + g;
          if (r_g >= M) continue;
          float v = acc[i][j][g] + bv;
          if (RELU) v = fmaxf(v, 0.f);
          long long oidx = (long long)r_g * outLd + n_g;
          if (OBF16) ((unsigned short*)op)[oidx] = f2bf(v);
          else       ((float*)op)[oidx] = v;
        }
      }
    }
  }
}

// Standalone GEMM wrapper (used for G).
// REMAP8: flat 1D launch; by = lin&7 pins each B-panel to one XCD's L2 (T1),
//         bx/bz from lin>>3; nz fixed at 2.
template<int BM, int BN, bool RELU, bool OBF16, bool TRANS, bool SPLITK, int NH,
         bool ROWPACK, bool DBUF, bool REMAP8>
__global__ __launch_bounds__(256)
void gemm_bt(const unsigned short* __restrict__ A,
             const unsigned short* __restrict__ A2,
             const unsigned short* __restrict__ Bt,
             const float* __restrict__ biasv,
             void* __restrict__ outp,
             void* __restrict__ outp2,
             int M, int Kchunk, int RPB, int EXTRA, int BSCALE,
             int nHalf, int bRowMask,
             long long bStrideB, long long outBatchStride, int outLd)
{
  constexpr int STAGE = DBUF ? 3 * (BM * 32 + BN * 32) : NH * (BM * 32 + BN * 32);
  constexpr int REPK = TRANS ? (BN / 2) * (BM + 8)
                     : (ROWPACK ? (BM > 64 ? (BM / 2) * (BN + 8) : BM * (BN + 8)) : 0);
  constexpr int SMEMN = (REPK > STAGE) ? REPK : STAGE;
  __shared__ unsigned short smem[SMEMN];
  int bx, by, bz, nz;
  if (REMAP8) {
    int lin = blockIdx.x;
    by = lin & 7;                 // XCD-local B panel
    int pos = lin >> 3;
    bz = pos >> 5;
    bx = pos & 31;
    nz = 2;
  } else {
    bx = blockIdx.x; by = blockIdx.y; bz = blockIdx.z; nz = gridDim.z;
  }
  gemm_core<BM, BN, RELU, OBF16, TRANS, SPLITK, NH, ROWPACK, DBUF>(
      bx, by, bz, nz, smem,
      A, A2, Bt, biasv, outp, outp2,
      M, Kchunk, RPB, EXTRA, BSCALE, nHalf, bRowMask,
      bStrideB, outBatchStride, outLd);
}

// cvt_x (unfused from mega): one row per block, pure streaming, tiny LDS ->
// unconstrained occupancy. xs[r,t]=bf16(x[r,t+1]) (0 at t=4095),
// xz[r,t]=bf16(x[r,t]) (0 at t=0), rs[r]=sum_t f32(xs[r,t]).
__global__ __launch_bounds__(256) void cvt_x(
    const float* __restrict__ x,
    unsigned short* __restrict__ xs,
    unsigned short* __restrict__ xz,
    float* __restrict__ rs)
{
  __shared__ float red[4];
  long long r = blockIdx.x;
  const float* xr = x + r * 4096;
  int t0 = threadIdx.x * 16;
  float v[17];
  const float4* xr4 = (const float4*)(xr + t0);
#pragma unroll
  for (int q = 0; q < 4; ++q) {
    float4 f = xr4[q];
    v[q * 4] = f.x; v[q * 4 + 1] = f.y; v[q * 4 + 2] = f.z; v[q * 4 + 3] = f.w;
  }
  v[16] = (t0 + 16 < 4096) ? xr[t0 + 16] : 0.f;
  unsigned int spk[8], zpk[8];
  float sum = 0.f;
#pragma unroll
  for (int q = 0; q < 8; ++q) {
    unsigned short s0 = f2bf(v[2 * q + 1]);
    unsigned short s1 = f2bf(v[2 * q + 2]);
    sum += bf2f(s0);
    sum += bf2f(s1);
    spk[q] = (unsigned int)s0 | ((unsigned int)s1 << 16);
    unsigned short z0 = (t0 == 0 && q == 0) ? (unsigned short)0 : f2bf(v[2 * q]);
    unsigned short z1 = f2bf(v[2 * q + 1]);
    zpk[q] = (unsigned int)z0 | ((unsigned int)z1 << 16);
  }
  *(uint4*)(xs + r * 4096 + t0)     = *(uint4*)(spk);
  *(uint4*)(xs + r * 4096 + t0 + 8) = *(uint4*)(spk + 4);
  *(uint4*)(xz + r * 4096 + t0)     = *(uint4*)(zpk);
  *(uint4*)(xz + r * 4096 + t0 + 8) = *(uint4*)(zpk + 4);
#pragma unroll
  for (int off = 32; off > 0; off >>= 1) sum += __shfl_down(sum, off);
  if ((threadIdx.x & 63) == 0) red[threadIdx.x >> 6] = sum;
  __syncthreads();
  if (threadIdx.x == 0) rs[r] = red[0] + red[1] + red[2] + red[3];
}

// conv1 (unfused from mega): blocks [0,1024) conv1-w (TRANS 128x128),
// [1024,1284) conv1-b (64x128). Both now 3-region counted-vmcnt pipelined
// (was 1-phase full-drain: 8 serial HBM latencies per block at K=256).
__global__ __launch_bounds__(256) void conv1(
    const unsigned short* __restrict__ zb,
    const unsigned short* __restrict__ w1T,
    const unsigned short* __restrict__ b1T,
    const float* __restrict__ wb1,
    const float* __restrict__ bb1,
    unsigned short* __restrict__ h1T,
    unsigned short* __restrict__ h1b)
{
  __shared__ unsigned short smem[24576];   // 3 regions x (128+128)*32 shorts
  int g = blockIdx.x;
  if (g < 1024) {
    // conv1-w -> h1T (TRANS, relu, DBUF): M=8*4096, K=256, A row=(r+2bb)*128
    gemm_core<128, 128, true, true, true, false, 1, false, true>(
        g & 255, g >> 8, 0, 1, smem,
        zb, nullptr, w1T, wb1, h1T, nullptr,
        32768, 256, 4096, 2, 128, 0, 0xFFFF, 0, 512ll * 4096, 4096);
  } else {
    int idx = g - 1024;
    // conv1-b (t<513): M=8*513, A row=(r+3585bb)*128 -> h1b bf16
    gemm_core<64, 128, true, true, false, false, 1, false, true>(
        idx % 65, idx / 65, 0, 1, smem,
        zb, nullptr, b1T, bb1, h1b, nullptr,
        4104, 256, 513, 3585, 128, 0, 0xFFFF, 0, 0, 512);
  }
}

// Fused final, 3 K-segments (K=3072):
//   k in [0,1024):    A=p0[r,k],                 B=w2T[n,k]
//   k in [1024,2048): A=p1[r,k-1024],            B=w2T[n,k-1024]
//   k in [2048,3072): A=h1b[(r+r/512)*512+k'],   B=b2T[n,k']     (k'=k-2048)
// out[r,n] = acc + rs[r]*wb2[n] + bb2[n].  BM=BN=64, glds staging.
// 3-region counted-vmcnt pipeline: region = one 64-k chunk (A0,A1,B0,B1),
// depth-2 prefetch, vmcnt(4)/raw-barrier — loads stay in flight across barriers.
__global__ __launch_bounds__(256) void final_gemm3(
    const unsigned short* __restrict__ p0,
    const unsigned short* __restrict__ p1,
    const unsigned short* __restrict__ h1b,
    const unsigned short* __restrict__ w2T,
    const unsigned short* __restrict__ b2T,
    const float* __restrict__ rs,
    const float* __restrict__ wb2,
    const float* __restrict__ bb2,
    float* __restrict__ out)
{
  constexpr int RS = 8192;                 // shorts: A0|A1|B0|B1 (2048 each)
  __shared__ unsigned short smem[3 * RS];
  const int tid = threadIdx.x;
  const int lane = tid & 63, wave = tid >> 6;
  const int wm = wave >> 1, wn = wave & 1;
  const int lr = lane & 15, quad = lane >> 4;
  const int r0 = blockIdx.x * 64, n0 = blockIdx.y * 64;

  const int srow = lane >> 2;
  const int sg = (lane & 3) ^ (srow & 3);
  const int row = wave * 16 + srow;
  const int rA = r0 + row;
  const int rB = n0 + row;
  const unsigned short* aP[3] = {
    p0 + (long long)rA * 1024 + sg * 8,
    p1 + (long long)rA * 1024 + sg * 8,
    h1b + ((long long)rA + (rA >> 9)) * 512 + sg * 8 };
  const unsigned short* bP[3] = {
    w2T + (long long)rB * 1024 + sg * 8,
    w2T + (long long)rB * 1024 + sg * 8,
    b2T + (long long)rB * 1024 + sg * 8 };

  int aoff[2], boff[2];
#pragma unroll
  for (int i = 0; i < 2; ++i) {
    int rr = wm * 32 + i * 16 + lr;
    aoff[i] = rr * 32 + ((quad ^ (rr & 3)) * 8);
    int nn = wn * 32 + i * 16 + lr;
    boff[i] = nn * 32 + ((quad ^ (nn & 3)) * 8);
  }

  float4v acc[2][2];
  const float4v z4 = {0.f, 0.f, 0.f, 0.f};
  acc[0][0] = z4; acc[0][1] = z4; acc[1][0] = z4; acc[1][1] = z4;

  const int wslot = wave * 512;
  auto stg = [&](int t, int m) {           // stage 64-k chunk t into region m
    int k = t * 64; int seg = k >> 10; int kk = k & 1023;
    unsigned short* base = smem + m * RS;
    __builtin_amdgcn_global_load_lds((gu32*)(aP[seg] + kk),      (lu32*)(base + wslot), 16, 0, 0);
    __builtin_amdgcn_global_load_lds((gu32*)(aP[seg] + kk + 32), (lu32*)(base + 2048 + wslot), 16, 0, 0);
    __builtin_amdgcn_global_load_lds((gu32*)(bP[seg] + kk),      (lu32*)(base + 4096 + wslot), 16, 0, 0);
    __builtin_amdgcn_global_load_lds((gu32*)(bP[seg] + kk + 32), (lu32*)(base + 6144 + wslot), 16, 0, 0);
  };
  stg(0, 0); stg(1, 1);
  int m = 0;
  for (int t = 0; t < 48; ++t) {
    if (t < 47) vmwait<4>();
    else        vmwait<0>();
    __builtin_amdgcn_s_barrier();
    __builtin_amdgcn_sched_barrier(0);
    int m2 = m + 2; if (m2 >= 3) m2 -= 3;
    if (t + 2 < 48) stg(t + 2, m2);
    const unsigned short* base = smem + m * RS;
#pragma unroll
    for (int h = 0; h < 2; ++h) {
      short8 af[2], bfr[2];
      af[0] = *(const short8*)(base + h * 2048 + aoff[0]);
      af[1] = *(const short8*)(base + h * 2048 + aoff[1]);
      bfr[0] = *(const short8*)(base + 4096 + h * 2048 + boff[0]);
      bfr[1] = *(const short8*)(base + 4096 + h * 2048 + boff[1]);
#pragma unroll
      for (int i = 0; i < 2; ++i)
#pragma unroll
        for (int j = 0; j < 2; ++j)
          acc[i][j] = __builtin_amdgcn_mfma_f32_16x16x32_bf16(af[i], bfr[j], acc[i][j], 0, 0, 0);
    }
    if (++m == 3) m = 0;
  }

#pragma unroll
  for (int j = 0; j < 2; ++j) {
    int n_g = n0 + wn * 32 + j * 16 + lr;
    float w2b = wb2[n_g], bbv = bb2[n_g];
#pragma unroll
    for (int i = 0; i < 2; ++i) {
      int rb2 = r0 + wm * 32 + i * 16 + quad * 4;
#pragma unroll
      for (int g = 0; g < 4; ++g) {
        int r_g = rb2 + g;
        out[(long long)r_g * 512 + n_g] = acc[i][j][g] + rs[r_g] * w2b + bbv;
      }
    }
  }
}

extern "C" void kernel_launch(void* const* d_in, const int* in_sizes, int n_in,
                              void* d_out, int out_size, void* d_ws, size_t ws_size,
                              hipStream_t stream) {
  const float* x   = (const float*)d_in[0];
  const float* z   = (const float*)d_in[1];
  const float* ww1 = (const float*)d_in[2];
  const float* wb1 = (const float*)d_in[3];
  const float* ww2 = (const float*)d_in[4];
  const float* wb2 = (const float*)d_in[5];
  const float* bw1 = (const float*)d_in[6];
  const float* bb1 = (const float*)d_in[7];
  const float* bw2 = (const float*)d_in[8];
  const float* bb2 = (const float*)d_in[9];

  char* ws = (char*)d_ws;
  unsigned short* xs  = (unsigned short*)ws; ws += 16777216ll * 2;  // (4096,4096) shifted bf16
  unsigned short* xz  = (unsigned short*)ws; ws += 16777216ll * 2;  // (4096,4096) t0-zeroed bf16
  unsigned short* zb  = (unsigned short*)ws; ws += 4196352ll  * 2;  // (8,4098,128) bf16; reused as p0
  unsigned short* h1T = (unsigned short*)ws; ws += 16777216ll * 2;  // (8,512,4096) h1 transposed bf16
  unsigned short* h1b = (unsigned short*)ws; ws += 2101248ll  * 2;  // (8,513,512) bias-path h1 bf16
  unsigned short* w2T = (unsigned short*)ws; ws += 524288ll * 2;    // (512,1024)
  unsigned short* b2T = (unsigned short*)ws; ws += 524288ll * 2;
  float* rs = (float*)ws;                    ws += 4096ll * 4;      // rowsum(xs)
  char* tail = ws;
  // w1T/b1T live until conv1 completes, then tail becomes p1
  unsigned short* w1T = (unsigned short*)tail;                      // (512,256)
  unsigned short* b1T = (unsigned short*)tail + 131072;             // (512,256)
  unsigned short* p0  = zb;                                         // (4096,1024) bf16 (zb dead by then)
  unsigned short* p1  = (unsigned short*)tail;                      // (4096,1024) bf16

  // 1) weights + z -> bf16 transposed
  prep_w<<<21512, 256, 0, stream>>>(ww1, ww2, bw1, bw2, z, w1T, w2T, b1T, b2T, zb);
  // 2) x -> xs/xz bf16 + rowsum (pure streaming, unconstrained occupancy)
  cvt_x<<<4096, 256, 0, stream>>>(x, xs, xz, rs);
  // 3) conv1-w + conv1-b, 3-region counted-vmcnt pipelined
  conv1<<<1284, 256, 0, stream>>>(zb, w1T, b1T, wb1, bb1, h1T, h1b);
  // 4) G = [xs ; xz] @ h1T^T, 128x128 tiles, 3-region counted-vmcnt pipeline,
  //    split-K x2 -> p0,p1 (bf16, ROWPACK): M=4096, N=1024, Kchunk=2048.
  //    Flat 512-block launch, by=lin&7 XCD-local B panels.
  gemm_bt<128, 128, false, true, false, true, 1, true, true, true><<<512, 256, 0, stream>>>(
      xs, xz, h1T, nullptr, p0, p1,
      4096, 2048, 512, 0, 4096, 512, 511, 512ll * 4096, 0, 1024);
  // 5) out = p0@w2 + p1@w2 + h1b-pair@b2 + rs x wb2 + bb2  (K=3072, 3-region pipe)
  final_gemm3<<<dim3(64, 8), 256, 0, stream>>>(
      p0, p1, h1b, w2T, b2T, rs, wb2, bb2, (float*)d_out);
}

// Round 5
// 232.945 us; speedup vs baseline: 1.0760x; 1.0760x over previous
//
#include <hip/hip_runtime.h>

typedef short short8 __attribute__((ext_vector_type(8)));
typedef float float4v __attribute__((ext_vector_type(4)));
typedef __attribute__((address_space(1))) const unsigned int gu32;
typedef __attribute__((address_space(3))) unsigned int lu32;

__device__ __forceinline__ unsigned short f2bf(float f) {
  unsigned int u = __builtin_bit_cast(unsigned int, f);
  u += 0x7FFFu + ((u >> 16) & 1u);   // round-to-nearest-even
  return (unsigned short)(u >> 16);
}
__device__ __forceinline__ float bf2f(unsigned short s) {
  return __builtin_bit_cast(float, (unsigned int)s << 16);
}

template<int N> __device__ __forceinline__ void vmwait() {
  if constexpr (N == 0) asm volatile("s_waitcnt vmcnt(0)" ::: "memory");
  else if constexpr (N == 2) asm volatile("s_waitcnt vmcnt(2)" ::: "memory");
  else if constexpr (N == 3) asm volatile("s_waitcnt vmcnt(3)" ::: "memory");
  else if constexpr (N == 4) asm volatile("s_waitcnt vmcnt(4)" ::: "memory");
  else if constexpr (N == 6) asm volatile("s_waitcnt vmcnt(6)" ::: "memory");
  else if constexpr (N == 8) asm volatile("s_waitcnt vmcnt(8)" ::: "memory");
}

// prep: blocks [0,320) LDS-tiled weight transposes (coalesced both sides —
// replaces prep_w's 2B scatter stores at stride 512B, ~16x write amplification);
// blocks [320,1345) zb bf16 convert; blocks [1345,5441) cvt_x rows.
__global__ __launch_bounds__(256) void prep(
    const float* __restrict__ ww1, const float* __restrict__ ww2,
    const float* __restrict__ bw1, const float* __restrict__ bw2,
    const float* __restrict__ z, const float* __restrict__ x,
    unsigned short* __restrict__ w1T, unsigned short* __restrict__ w2T,
    unsigned short* __restrict__ b1T, unsigned short* __restrict__ b2T,
    unsigned short* __restrict__ zb,
    unsigned short* __restrict__ xs, unsigned short* __restrict__ xz,
    float* __restrict__ rs)
{
  __shared__ float lds[64][65];
  const int b = blockIdx.x;
  const int tid = threadIdx.x;
  if (b < 320) {
    // 64x64 tile transpose: src (K rows, 512 cols f32) -> dst (512 rows, K cols bf16)
    const float* src; unsigned short* dst; int K, tile;
    if (b < 32)       { src = ww1; dst = w1T; K = 256;  tile = b; }
    else if (b < 160) { src = ww2; dst = w2T; K = 1024; tile = b - 32; }
    else if (b < 192) { src = bw1; dst = b1T; K = 256;  tile = b - 160; }
    else              { src = bw2; dst = b2T; K = 1024; tile = b - 192; }
    int ntk = K >> 6;
    int k0 = (tile % ntk) * 64, n0 = (tile / ntk) * 64;
    int nl = tid & 63, kh = tid >> 6;
#pragma unroll
    for (int p = 0; p < 16; ++p)
      lds[kh * 16 + p][nl] = src[(long long)(k0 + kh * 16 + p) * 512 + n0 + nl];
    __syncthreads();
    int nr = tid >> 2, q = tid & 3;          // 64 n-rows x 4 threads, 16 k each
    unsigned short tmp[16];
#pragma unroll
    for (int u = 0; u < 16; ++u) tmp[u] = f2bf(lds[q * 16 + u][nr]);
    unsigned short* op = dst + (long long)(n0 + nr) * K + k0 + q * 16;
    *(uint4*)op = *(uint4*)tmp;
    *(uint4*)(op + 8) = *(uint4*)(tmp + 8);
  } else if (b < 1345) {
    // zb[j] = bf16(z[j]), 16 elems/thread vectorized
    long long base = (long long)(b - 320) * 4096 + tid * 16;
    if (base < 4196352) {
      const float4* zp = (const float4*)(z + base);
      unsigned int pk[8];
#pragma unroll
      for (int q2 = 0; q2 < 4; ++q2) {
        float4 f = zp[q2];
        pk[q2 * 2]     = (unsigned int)f2bf(f.x) | ((unsigned int)f2bf(f.y) << 16);
        pk[q2 * 2 + 1] = (unsigned int)f2bf(f.z) | ((unsigned int)f2bf(f.w) << 16);
      }
      *(uint4*)(zb + base)     = *(uint4*)pk;
      *(uint4*)(zb + base + 8) = *(uint4*)(pk + 4);
    }
  } else {
    // cvt_x: xs[r,t]=bf16(x[r,t+1]) (0 at t=4095), xz[r,t]=bf16(x[r,t]) (0 at t=0),
    // rs[r]=sum_t f32(xs[r,t])
    float* red = &lds[0][0];
    long long r = b - 1345;
    const float* xr = x + r * 4096;
    int t0 = tid * 16;
    float v[17];
    const float4* xr4 = (const float4*)(xr + t0);
#pragma unroll
    for (int q = 0; q < 4; ++q) {
      float4 f = xr4[q];
      v[q * 4] = f.x; v[q * 4 + 1] = f.y; v[q * 4 + 2] = f.z; v[q * 4 + 3] = f.w;
    }
    v[16] = (t0 + 16 < 4096) ? xr[t0 + 16] : 0.f;
    unsigned int spk[8], zpk[8];
    float sum = 0.f;
#pragma unroll
    for (int q = 0; q < 8; ++q) {
      unsigned short s0 = f2bf(v[2 * q + 1]);
      unsigned short s1 = f2bf(v[2 * q + 2]);
      sum += bf2f(s0);
      sum += bf2f(s1);
      spk[q] = (unsigned int)s0 | ((unsigned int)s1 << 16);
      unsigned short z0 = (t0 == 0 && q == 0) ? (unsigned short)0 : f2bf(v[2 * q]);
      unsigned short z1 = f2bf(v[2 * q + 1]);
      zpk[q] = (unsigned int)z0 | ((unsigned int)z1 << 16);
    }
    *(uint4*)(xs + r * 4096 + t0)     = *(uint4*)(spk);
    *(uint4*)(xs + r * 4096 + t0 + 8) = *(uint4*)(spk + 4);
    *(uint4*)(xz + r * 4096 + t0)     = *(uint4*)(zpk);
    *(uint4*)(xz + r * 4096 + t0 + 8) = *(uint4*)(zpk + 4);
#pragma unroll
    for (int off = 32; off > 0; off >>= 1) sum += __shfl_down(sum, off);
    if ((tid & 63) == 0) red[tid >> 6] = sum;
    __syncthreads();
    if (tid == 0) rs[r] = red[0] + red[1] + red[2] + red[3];
  }
}

// Unified GEMM core, glds(16B) staging, XOR-swizzled unpadded LDS.
// C[r,n] = act(biasv[n] + sum_k Ae[base(r)+kOff+k] * Bt[((n)&bRowMask)*Ktot + bOffB + kOff + k])
// base(r) = (r + (r/RPB)*EXTRA) * BSCALE;  Ae = (nHalf && n0>=nHalf) ? A2 : A.
// SPLITK: bz picks k-chunk; partial -> outp/outp2 (bf16).
// NREG>0: NREG-region counted-vmcnt pipeline (T4): depth-(NREG-2) prefetch ahead,
//   raw s_barrier, vmcnt((NREG-2)*(AI+BI)) — loads stay in flight across barriers.
// NREG==0: BK=32*NH, stage-all -> barrier -> compute-all (1-phase).
// TRANS: out[bb*outBatchStride + (n0+f)*outLd + t_local] (bf16 via 2-pass LDS repack).
// ROWPACK: row-major bf16 store via LDS repack (stride BN+8), 2-pass when BM>64.
template<int BM, int BN, bool RELU, bool OBF16, bool TRANS, bool SPLITK, int NH,
         bool ROWPACK, int NREG>
__device__ __forceinline__ void gemm_core(
    int bx, int by, int bz, int nzTot, unsigned short* smem,
    const unsigned short* __restrict__ A,
    const unsigned short* __restrict__ A2,
    const unsigned short* __restrict__ Bt,
    const float* __restrict__ biasv,
    void* __restrict__ outp,
    void* __restrict__ outp2,
    int M, int Kchunk, int RPB, int EXTRA, int BSCALE,
    int nHalf, int bRowMask,
    long long bStrideB, long long outBatchStride, int outLd)
{
  constexpr int WM = BM / 2, WN = BN / 2;
  constexpr int NI = WM / 16, NJ = WN / 16;
  constexpr int AI = BM / 64;                 // glds instrs per wave per 32-chunk
  constexpr int BI = BN / 64;
  constexpr int SA1 = BM * 32, SB1 = BN * 32; // one 32-chunk region (shorts)
  unsigned short* sB0 = smem + (NREG > 0 ? 1 : NH) * SA1;

  const int tid  = threadIdx.x;
  const int lane = tid & 63;
  const int wave = tid >> 6;
  const int wm = wave >> 1, wn = wave & 1;
  const int lr = lane & 15, quad = lane >> 4;

  const int r0 = bx * BM;
  const int n0 = by * BN;
  const int bb = r0 / RPB;
  const int Ktot = SPLITK ? Kchunk * nzTot : Kchunk;
  const int kOff = SPLITK ? bz * Kchunk : 0;
  const long long bOffB = (long long)bb * bStrideB;
  const unsigned short* Ae = (nHalf && n0 >= nHalf) ? A2 : A;

  const int srow = lane >> 2;
  const int sg = (lane & 3) ^ (srow & 3);     // XOR swizzle on fetch side
  const unsigned short* gA[AI];
#pragma unroll
  for (int c = 0; c < AI; ++c) {
    int instr = c * 4 + wave;
    int row = instr * 16 + srow;
    int r = r0 + row; if (r > M - 1) r = M - 1;          // clamp partial tiles
    gA[c] = Ae + ((long long)r + (long long)(r / RPB) * EXTRA) * BSCALE + kOff + sg * 8;
  }
  const unsigned short* gB[BI];
#pragma unroll
  for (int c = 0; c < BI; ++c) {
    int instr = c * 4 + wave;
    int row = instr * 16 + srow;
    gB[c] = Bt + (long long)((n0 + row) & bRowMask) * Ktot + bOffB + kOff + sg * 8;
  }

  int aoff[NI], boff[NJ];
#pragma unroll
  for (int i = 0; i < NI; ++i) {
    int rr = wm * WM + i * 16 + lr;
    aoff[i] = rr * 32 + ((quad ^ (rr & 3)) * 8);
  }
#pragma unroll
  for (int j = 0; j < NJ; ++j) {
    int rr = wn * WN + j * 16 + lr;
    boff[j] = rr * 32 + ((quad ^ (rr & 3)) * 8);
  }

  float4v acc[NI][NJ];
  const float4v z4 = {0.f, 0.f, 0.f, 0.f};
#pragma unroll
  for (int i = 0; i < NI; ++i)
#pragma unroll
    for (int j = 0; j < NJ; ++j) acc[i][j] = z4;

  if constexpr (NREG > 0) {
    // NREG-region pipeline: region m holds one 32-chunk (A at +0, B at +SA1).
    constexpr int RS = SA1 + SB1;
    const int NT = Kchunk >> 5;
    auto stg = [&](int t, int m) {
      unsigned short* rb = smem + m * RS;
      int kk = t * 32;
#pragma unroll
      for (int c = 0; c < AI; ++c)
        __builtin_amdgcn_global_load_lds((gu32*)(gA[c] + kk),
                                         (lu32*)(rb + (c * 4 + wave) * 512), 16, 0, 0);
#pragma unroll
      for (int c = 0; c < BI; ++c)
        __builtin_amdgcn_global_load_lds((gu32*)(gB[c] + kk),
                                         (lu32*)(rb + SA1 + (c * 4 + wave) * 512), 16, 0, 0);
    };
#pragma unroll
    for (int i = 0; i < NREG - 1; ++i) if (i < NT) stg(i, i);
    int m = 0;
    for (int t = 0; t < NT; ++t) {
      if (NREG == 4 && t + 3 <= NT) vmwait<2 * (AI + BI)>();
      else if (t + 2 <= NT)         vmwait<AI + BI>();
      else                          vmwait<0>();
      __builtin_amdgcn_s_barrier();
      __builtin_amdgcn_sched_barrier(0);     // no ds_read may hoist above barrier
      int m2 = m + NREG - 1; if (m2 >= NREG) m2 -= NREG;
      if (t + NREG - 1 < NT) stg(t + NREG - 1, m2);
      const unsigned short* rb = smem + m * RS;
      short8 af[NI], bfr[NJ];
#pragma unroll
      for (int i = 0; i < NI; ++i) af[i] = *(const short8*)(rb + aoff[i]);
#pragma unroll
      for (int j = 0; j < NJ; ++j) bfr[j] = *(const short8*)(rb + SA1 + boff[j]);
#pragma unroll
      for (int i = 0; i < NI; ++i)
#pragma unroll
        for (int j = 0; j < NJ; ++j)
          acc[i][j] = __builtin_amdgcn_mfma_f32_16x16x32_bf16(af[i], bfr[j], acc[i][j], 0, 0, 0);
      if (++m == NREG) m = 0;
    }
    __syncthreads();                         // all reads done before epilogue reuses LDS
  } else {
    for (int k0 = 0; k0 < Kchunk; k0 += 32 * NH) {
#pragma unroll
      for (int h = 0; h < NH; ++h) {
#pragma unroll
        for (int c = 0; c < AI; ++c)
          __builtin_amdgcn_global_load_lds((gu32*)(gA[c] + k0 + h * 32),
                                           (lu32*)(smem + (c * 4 + wave) * 512 + h * SA1), 16, 0, 0);
#pragma unroll
        for (int c = 0; c < BI; ++c)
          __builtin_amdgcn_global_load_lds((gu32*)(gB[c] + k0 + h * 32),
                                           (lu32*)(sB0 + (c * 4 + wave) * 512 + h * SB1), 16, 0, 0);
      }
      __syncthreads();
#pragma unroll
      for (int h = 0; h < NH; ++h) {
        short8 af[NI], bfr[NJ];
#pragma unroll
        for (int i = 0; i < NI; ++i) af[i] = *(const short8*)(smem + h * SA1 + aoff[i]);
#pragma unroll
        for (int j = 0; j < NJ; ++j) bfr[j] = *(const short8*)(sB0 + h * SB1 + boff[j]);
#pragma unroll
        for (int i = 0; i < NI; ++i)
#pragma unroll
          for (int j = 0; j < NJ; ++j)
            acc[i][j] = __builtin_amdgcn_mfma_f32_16x16x32_bf16(af[i], bfr[j], acc[i][j], 0, 0, 0);
      }
      __syncthreads();
    }
  }

  if (TRANS) {
    // 2-pass repack: pass p handles f-rows [p*WN, p*WN+WN) in a [WN][BM+8] buffer.
    unsigned short* Ts = smem;
    const int t0l = r0 - bb * RPB;
#pragma unroll
    for (int p = 0; p < 2; ++p) {
      if (wn == p) {
#pragma unroll
        for (int j = 0; j < NJ; ++j) {
          int frl = j * 16 + lr;                     // local f row in [0,WN)
          float bv = biasv[n0 + p * WN + frl];
#pragma unroll
          for (int i = 0; i < NI; ++i) {
            int tr = wm * WM + i * 16 + quad * 4;
            unsigned long long pk = 0;
#pragma unroll
            for (int g = 0; g < 4; ++g) {
              float vv = acc[i][j][g] + bv;
              if (RELU) vv = fmaxf(vv, 0.f);
              pk |= (unsigned long long)f2bf(vv) << (16 * g);
            }
            *(unsigned long long*)(Ts + frl * (BM + 8) + tr) = pk;
          }
        }
      }
      __syncthreads();
      // 256 threads store WN=64 rows x BM elements: 4 threads/row, BM/4 elems each
      int frl = tid >> 2, sgg = tid & 3;
      unsigned short* dst = (unsigned short*)outp + (long long)bb * outBatchStride
                          + (long long)(n0 + p * WN + frl) * outLd + t0l + sgg * (BM / 4);
      const unsigned short* srcp = Ts + frl * (BM + 8) + sgg * (BM / 4);
#pragma unroll
      for (int u = 0; u < BM / 32; ++u)
        *(uint4*)(dst + u * 8) = *(const uint4*)(srcp + u * 8);
      __syncthreads();
    }
  } else if (ROWPACK) {
    // row-major bf16 store via LDS repack (stride BN+8) + dwordx4.
    // 2-pass over row-halves when BM>64 so the buffer fits under the stage LDS.
    constexpr int P  = (BM > 64) ? 2 : 1;
    constexpr int RP = BM / P;                // rows per pass
    constexpr int BNP = BN + 8;
    constexpr int TPR = 256 / RP;             // threads per output row
    constexpr int EPT = BN / TPR;             // elements per thread
    void* op = (SPLITK && bz) ? outp2 : outp;
    unsigned short* R = smem;
#pragma unroll
    for (int p = 0; p < P; ++p) {
      if (P == 1 || wm == p) {
#pragma unroll
        for (int j = 0; j < NJ; ++j) {
          int cc = wn * WN + j * 16 + lr;
#pragma unroll
          for (int i = 0; i < NI; ++i) {
            int rl = (P == 1 ? wm * WM : 0) + i * 16 + quad * 4;
#pragma unroll
            for (int g = 0; g < 4; ++g)
              R[(rl + g) * BNP + cc] = f2bf(acc[i][j][g]);
          }
        }
      }
      __syncthreads();
      int rloc = tid / TPR, part = tid % TPR;
      unsigned short* dstp = (unsigned short*)op
                           + (long long)(r0 + p * RP + rloc) * outLd + n0 + part * EPT;
      const unsigned short* srcp = R + rloc * BNP + part * EPT;
#pragma unroll
      for (int u = 0; u < EPT / 8; ++u)
        *(uint4*)(dstp + u * 8) = *(const uint4*)(srcp + u * 8);
      if (p + 1 < P) __syncthreads();
    }
  } else {
    void* op = (SPLITK && bz) ? outp2 : outp;
#pragma unroll
    for (int j = 0; j < NJ; ++j) {
      int n_g = n0 + wn * WN + j * 16 + lr;
      float bv = biasv ? biasv[n_g] : 0.f;
#pragma unroll
      for (int i = 0; i < NI; ++i) {
        int r_base = r0 + wm * WM + i * 16 + quad * 4;
#pragma unroll
        for (int g = 0; g < 4; ++g) {
          int r_g = r_base + g;
          if (r_g >= M) continue;
          float v = acc[i][j][g] + bv;
          if (RELU) v = fmaxf(v, 0.f);
          long long oidx = (long long)r_g * outLd + n_g;
          if (OBF16) ((unsigned short*)op)[oidx] = f2bf(v);
          else       ((float*)op)[oidx] = v;
        }
      }
    }
  }
}

// Standalone GEMM wrapper (used for G).
// REMAP: flat 1D launch; bx = (lin&7)*4 + ((lin>>3)&3) pins one BATCH per XCD:
//   its 4 MB h1T panel lives in that XCD's L2, and all 4 by-consumers of each
//   A chunk share the same L2 (R4's by-pinning streamed 32 MB A per XCD with
//   zero L2 reuse -> FETCH 165 MB).
template<int BM, int BN, bool RELU, bool OBF16, bool TRANS, bool SPLITK, int NH,
         bool ROWPACK, int NREG, bool REMAP>
__global__ __launch_bounds__(256)
void gemm_bt(const unsigned short* __restrict__ A,
             const unsigned short* __restrict__ A2,
             const unsigned short* __restrict__ Bt,
             const float* __restrict__ biasv,
             void* __restrict__ outp,
             void* __restrict__ outp2,
             int M, int Kchunk, int RPB, int EXTRA, int BSCALE,
             int nHalf, int bRowMask,
             long long bStrideB, long long outBatchStride, int outLd)
{
  constexpr int STAGE = (NREG > 0 ? NREG : NH) * (BM * 32 + BN * 32);
  constexpr int REPK = TRANS ? (BN / 2) * (BM + 8)
                     : (ROWPACK ? (BM > 64 ? (BM / 2) * (BN + 8) : BM * (BN + 8)) : 0);
  constexpr int SMEMN = (REPK > STAGE) ? REPK : STAGE;
  __shared__ unsigned short smem[SMEMN];
  int bx, by, bz, nz;
  if (REMAP) {
    int lin = blockIdx.x;
    bx = (lin & 7) * 4 + ((lin >> 3) & 3);   // batch bb = bx/4 = XCD id
    by = (lin >> 5) & 7;
    bz = lin >> 8;
    nz = 2;
  } else {
    bx = blockIdx.x; by = blockIdx.y; bz = blockIdx.z; nz = gridDim.z;
  }
  gemm_core<BM, BN, RELU, OBF16, TRANS, SPLITK, NH, ROWPACK, NREG>(
      bx, by, bz, nz, smem,
      A, A2, Bt, biasv, outp, outp2,
      M, Kchunk, RPB, EXTRA, BSCALE, nHalf, bRowMask,
      bStrideB, outBatchStride, outLd);
}

// conv1: blocks [0,1024) conv1-w (TRANS 128x128), [1024,1284) conv1-b (64x128).
// 3-region counted-vmcnt pipelined (48 KB LDS -> 3 blocks/CU).
__global__ __launch_bounds__(256) void conv1(
    const unsigned short* __restrict__ zb,
    const unsigned short* __restrict__ w1T,
    const unsigned short* __restrict__ b1T,
    const float* __restrict__ wb1,
    const float* __restrict__ bb1,
    unsigned short* __restrict__ h1T,
    unsigned short* __restrict__ h1b)
{
  __shared__ unsigned short smem[24576];   // 3 regions x (128+128)*32 shorts
  int g = blockIdx.x;
  if (g < 1024) {
    // conv1-w -> h1T (TRANS, relu): M=8*4096, K=256, A row=(r+2bb)*128
    gemm_core<128, 128, true, true, true, false, 1, false, 3>(
        g & 255, g >> 8, 0, 1, smem,
        zb, nullptr, w1T, wb1, h1T, nullptr,
        32768, 256, 4096, 2, 128, 0, 0xFFFF, 0, 512ll * 4096, 4096);
  } else {
    int idx = g - 1024;
    // conv1-b (t<513): M=8*513, A row=(r+3585bb)*128 -> h1b bf16
    gemm_core<64, 128, true, true, false, false, 1, false, 3>(
        idx % 65, idx / 65, 0, 1, smem,
        zb, nullptr, b1T, bb1, h1b, nullptr,
        4104, 256, 513, 3585, 128, 0, 0xFFFF, 0, 0, 512);
  }
}

// Fused final, 3 K-segments (K=3072):
//   k in [0,1024):    A=p0[r,k],                 B=w2T[n,k]
//   k in [1024,2048): A=p1[r,k-1024],            B=w2T[n,k-1024]
//   k in [2048,3072): A=h1b[(r+r/512)*512+k'],   B=b2T[n,k']     (k'=k-2048)
// out[r,n] = acc + rs[r]*wb2[n] + bb2[n].  BM=BN=64, glds staging.
// 4-region counted-vmcnt pipeline: region = one 64-k chunk (A0,A1,B0,B1),
// depth-2-ahead prefetch, vmcnt(8)/raw-barrier.
__global__ __launch_bounds__(256) void final_gemm3(
    const unsigned short* __restrict__ p0,
    const unsigned short* __restrict__ p1,
    const unsigned short* __restrict__ h1b,
    const unsigned short* __restrict__ w2T,
    const unsigned short* __restrict__ b2T,
    const float* __restrict__ rs,
    const float* __restrict__ wb2,
    const float* __restrict__ bb2,
    float* __restrict__ out)
{
  constexpr int RS = 8192;                 // shorts: A0|A1|B0|B1 (2048 each)
  __shared__ unsigned short smem[4 * RS];  // 64 KB, 2 blocks/CU
  const int tid = threadIdx.x;
  const int lane = tid & 63, wave = tid >> 6;
  const int wm = wave >> 1, wn = wave & 1;
  const int lr = lane & 15, quad = lane >> 4;
  const int r0 = blockIdx.x * 64, n0 = blockIdx.y * 64;

  const int srow = lane >> 2;
  const int sg = (lane & 3) ^ (srow & 3);
  const int row = wave * 16 + srow;
  const int rA = r0 + row;
  const int rB = n0 + row;
  const unsigned short* aP[3] = {
    p0 + (long long)rA * 1024 + sg * 8,
    p1 + (long long)rA * 1024 + sg * 8,
    h1b + ((long long)rA + (rA >> 9)) * 512 + sg * 8 };
  const unsigned short* bP[3] = {
    w2T + (long long)rB * 1024 + sg * 8,
    w2T + (long long)rB * 1024 + sg * 8,
    b2T + (long long)rB * 1024 + sg * 8 };

  int aoff[2], boff[2];
#pragma unroll
  for (int i = 0; i < 2; ++i) {
    int rr = wm * 32 + i * 16 + lr;
    aoff[i] = rr * 32 + ((quad ^ (rr & 3)) * 8);
    int nn = wn * 32 + i * 16 + lr;
    boff[i] = nn * 32 + ((quad ^ (nn & 3)) * 8);
  }

  float4v acc[2][2];
  const float4v z4 = {0.f, 0.f, 0.f, 0.f};
  acc[0][0] = z4; acc[0][1] = z4; acc[1][0] = z4; acc[1][1] = z4;

  const int wslot = wave * 512;
  auto stg = [&](int t, int m) {           // stage 64-k chunk t into region m
    int k = t * 64; int seg = k >> 10; int kk = k & 1023;
    unsigned short* base = smem + m * RS;
    __builtin_amdgcn_global_load_lds((gu32*)(aP[seg] + kk),      (lu32*)(base + wslot), 16, 0, 0);
    __builtin_amdgcn_global_load_lds((gu32*)(aP[seg] + kk + 32), (lu32*)(base + 2048 + wslot), 16, 0, 0);
    __builtin_amdgcn_global_load_lds((gu32*)(bP[seg] + kk),      (lu32*)(base + 4096 + wslot), 16, 0, 0);
    __builtin_amdgcn_global_load_lds((gu32*)(bP[seg] + kk + 32), (lu32*)(base + 6144 + wslot), 16, 0, 0);
  };
  stg(0, 0); stg(1, 1); stg(2, 2);
  int m = 0;
  for (int t = 0; t < 48; ++t) {
    if (t <= 45)      vmwait<8>();
    else if (t == 46) vmwait<4>();
    else              vmwait<0>();
    __builtin_amdgcn_s_barrier();
    __builtin_amdgcn_sched_barrier(0);
    int m2 = m + 3; if (m2 >= 4) m2 -= 4;
    if (t + 3 < 48) stg(t + 3, m2);
    const unsigned short* base = smem + m * RS;
#pragma unroll
    for (int h = 0; h < 2; ++h) {
      short8 af[2], bfr[2];
      af[0] = *(const short8*)(base + h * 2048 + aoff[0]);
      af[1] = *(const short8*)(base + h * 2048 + aoff[1]);
      bfr[0] = *(const short8*)(base + 4096 + h * 2048 + boff[0]);
      bfr[1] = *(const short8*)(base + 4096 + h * 2048 + boff[1]);
#pragma unroll
      for (int i = 0; i < 2; ++i)
#pragma unroll
        for (int j = 0; j < 2; ++j)
          acc[i][j] = __builtin_amdgcn_mfma_f32_16x16x32_bf16(af[i], bfr[j], acc[i][j], 0, 0, 0);
    }
    if (++m == 4) m = 0;
  }

#pragma unroll
  for (int j = 0; j < 2; ++j) {
    int n_g = n0 + wn * 32 + j * 16 + lr;
    float w2b = wb2[n_g], bbv = bb2[n_g];
#pragma unroll
    for (int i = 0; i < 2; ++i) {
      int rb2 = r0 + wm * 32 + i * 16 + quad * 4;
#pragma unroll
      for (int g = 0; g < 4; ++g) {
        int r_g = rb2 + g;
        out[(long long)r_g * 512 + n_g] = acc[i][j][g] + rs[r_g] * w2b + bbv;
      }
    }
  }
}

extern "C" void kernel_launch(void* const* d_in, const int* in_sizes, int n_in,
                              void* d_out, int out_size, void* d_ws, size_t ws_size,
                              hipStream_t stream) {
  const float* x   = (const float*)d_in[0];
  const float* z   = (const float*)d_in[1];
  const float* ww1 = (const float*)d_in[2];
  const float* wb1 = (const float*)d_in[3];
  const float* ww2 = (const float*)d_in[4];
  const float* wb2 = (const float*)d_in[5];
  const float* bw1 = (const float*)d_in[6];
  const float* bb1 = (const float*)d_in[7];
  const float* bw2 = (const float*)d_in[8];
  const float* bb2 = (const float*)d_in[9];

  char* ws = (char*)d_ws;
  unsigned short* xs  = (unsigned short*)ws; ws += 16777216ll * 2;  // (4096,4096) shifted bf16
  unsigned short* xz  = (unsigned short*)ws; ws += 16777216ll * 2;  // (4096,4096) t0-zeroed bf16
  unsigned short* zb  = (unsigned short*)ws; ws += 4196352ll  * 2;  // (8,4098,128) bf16; reused as p0
  unsigned short* h1T = (unsigned short*)ws; ws += 16777216ll * 2;  // (8,512,4096) h1 transposed bf16
  unsigned short* h1b = (unsigned short*)ws; ws += 2101248ll  * 2;  // (8,513,512) bias-path h1 bf16
  unsigned short* w2T = (unsigned short*)ws; ws += 524288ll * 2;    // (512,1024)
  unsigned short* b2T = (unsigned short*)ws; ws += 524288ll * 2;
  float* rs = (float*)ws;                    ws += 4096ll * 4;      // rowsum(xs)
  char* tail = ws;
  // w1T/b1T live until conv1 completes, then tail becomes p1
  unsigned short* w1T = (unsigned short*)tail;                      // (512,256)
  unsigned short* b1T = (unsigned short*)tail + 131072;             // (512,256)
  unsigned short* p0  = zb;                                         // (4096,1024) bf16 (zb dead by then)
  unsigned short* p1  = (unsigned short*)tail;                      // (4096,1024) bf16

  // 1) weights/z prep (LDS-tiled transposes) + x -> xs/xz + rowsum, one dispatch
  prep<<<5441, 256, 0, stream>>>(ww1, ww2, bw1, bw2, z, x,
                                 w1T, w2T, b1T, b2T, zb, xs, xz, rs);
  // 2) conv1-w + conv1-b, 3-region counted-vmcnt pipelined
  conv1<<<1284, 256, 0, stream>>>(zb, w1T, b1T, wb1, bb1, h1T, h1b);
  // 3) G = [xs ; xz] @ h1T^T, 128x128 tiles, 4-region depth-3 pipeline,
  //    split-K x2 -> p0,p1 (bf16, ROWPACK): M=4096, N=1024, Kchunk=2048.
  //    Flat 512-block launch, batch-per-XCD remap.
  gemm_bt<128, 128, false, true, false, true, 1, true, 4, true><<<512, 256, 0, stream>>>(
      xs, xz, h1T, nullptr, p0, p1,
      4096, 2048, 512, 0, 4096, 512, 511, 512ll * 4096, 0, 1024);
  // 4) out = p0@w2 + p1@w2 + h1b-pair@b2 + rs x wb2 + bb2  (K=3072, 4-region pipe)
  final_gemm3<<<dim3(64, 8), 256, 0, stream>>>(
      p0, p1, h1b, w2T, b2T, rs, wb2, bb2, (float*)d_out);
}

// Round 6
// 229.055 us; speedup vs baseline: 1.0943x; 1.0170x over previous
//
#include <hip/hip_runtime.h>

typedef short short8 __attribute__((ext_vector_type(8)));
typedef float float4v __attribute__((ext_vector_type(4)));
typedef __attribute__((address_space(1))) const unsigned int gu32;
typedef __attribute__((address_space(3))) unsigned int lu32;

__device__ __forceinline__ unsigned short f2bf(float f) {
  unsigned int u = __builtin_bit_cast(unsigned int, f);
  u += 0x7FFFu + ((u >> 16) & 1u);   // round-to-nearest-even
  return (unsigned short)(u >> 16);
}
__device__ __forceinline__ float bf2f(unsigned short s) {
  return __builtin_bit_cast(float, (unsigned int)s << 16);
}

template<int N> __device__ __forceinline__ void vmwait() {
  if constexpr (N == 0) asm volatile("s_waitcnt vmcnt(0)" ::: "memory");
  else if constexpr (N == 2) asm volatile("s_waitcnt vmcnt(2)" ::: "memory");
  else if constexpr (N == 3) asm volatile("s_waitcnt vmcnt(3)" ::: "memory");
  else if constexpr (N == 4) asm volatile("s_waitcnt vmcnt(4)" ::: "memory");
  else if constexpr (N == 6) asm volatile("s_waitcnt vmcnt(6)" ::: "memory");
  else if constexpr (N == 8) asm volatile("s_waitcnt vmcnt(8)" ::: "memory");
}

// LDS group swizzle: row r, natural group g lives at position g ^ SWZ(r).
// SWZ(r) = (r&3) ^ ((r>>2)&3): bank-quad = (4*(r&1) + pos) mod 8 then takes each
// value exactly 2x across any 16 rows -> 2-way aliasing only (free on CDNA4).
// The old (r&3)-only form gave 4-way conflicts (rows 0,4,8,12 same bank quad),
// measured 4.19M conflict cycles/dispatch on gemm_bt.
__device__ __forceinline__ int rswz(int r) { return (r & 3) ^ ((r >> 2) & 3); }

// prep: blocks [0,320) LDS-tiled weight transposes (coalesced both sides);
// blocks [320,1345) zb bf16 convert; blocks [1345,5441) cvt_x rows.
__global__ __launch_bounds__(256) void prep(
    const float* __restrict__ ww1, const float* __restrict__ ww2,
    const float* __restrict__ bw1, const float* __restrict__ bw2,
    const float* __restrict__ z, const float* __restrict__ x,
    unsigned short* __restrict__ w1T, unsigned short* __restrict__ w2T,
    unsigned short* __restrict__ b1T, unsigned short* __restrict__ b2T,
    unsigned short* __restrict__ zb,
    unsigned short* __restrict__ xs, unsigned short* __restrict__ xz,
    float* __restrict__ rs)
{
  __shared__ float lds[64][65];
  const int b = blockIdx.x;
  const int tid = threadIdx.x;
  if (b < 320) {
    // 64x64 tile transpose: src (K rows, 512 cols f32) -> dst (512 rows, K cols bf16)
    const float* src; unsigned short* dst; int K, tile;
    if (b < 32)       { src = ww1; dst = w1T; K = 256;  tile = b; }
    else if (b < 160) { src = ww2; dst = w2T; K = 1024; tile = b - 32; }
    else if (b < 192) { src = bw1; dst = b1T; K = 256;  tile = b - 160; }
    else              { src = bw2; dst = b2T; K = 1024; tile = b - 192; }
    int ntk = K >> 6;
    int k0 = (tile % ntk) * 64, n0 = (tile / ntk) * 64;
    int nl = tid & 63, kh = tid >> 6;
#pragma unroll
    for (int p = 0; p < 16; ++p)
      lds[kh * 16 + p][nl] = src[(long long)(k0 + kh * 16 + p) * 512 + n0 + nl];
    __syncthreads();
    int nr = tid >> 2, q = tid & 3;          // 64 n-rows x 4 threads, 16 k each
    unsigned short tmp[16];
#pragma unroll
    for (int u = 0; u < 16; ++u) tmp[u] = f2bf(lds[q * 16 + u][nr]);
    unsigned short* op = dst + (long long)(n0 + nr) * K + k0 + q * 16;
    *(uint4*)op = *(uint4*)tmp;
    *(uint4*)(op + 8) = *(uint4*)(tmp + 8);
  } else if (b < 1345) {
    // zb[j] = bf16(z[j]), 16 elems/thread vectorized
    long long base = (long long)(b - 320) * 4096 + tid * 16;
    if (base < 4196352) {
      const float4* zp = (const float4*)(z + base);
      unsigned int pk[8];
#pragma unroll
      for (int q2 = 0; q2 < 4; ++q2) {
        float4 f = zp[q2];
        pk[q2 * 2]     = (unsigned int)f2bf(f.x) | ((unsigned int)f2bf(f.y) << 16);
        pk[q2 * 2 + 1] = (unsigned int)f2bf(f.z) | ((unsigned int)f2bf(f.w) << 16);
      }
      *(uint4*)(zb + base)     = *(uint4*)pk;
      *(uint4*)(zb + base + 8) = *(uint4*)(pk + 4);
    }
  } else {
    // cvt_x: xs[r,t]=bf16(x[r,t+1]) (0 at t=4095), xz[r,t]=bf16(x[r,t]) (0 at t=0),
    // rs[r]=sum_t f32(xs[r,t])
    float* red = &lds[0][0];
    long long r = b - 1345;
    const float* xr = x + r * 4096;
    int t0 = tid * 16;
    float v[17];
    const float4* xr4 = (const float4*)(xr + t0);
#pragma unroll
    for (int q = 0; q < 4; ++q) {
      float4 f = xr4[q];
      v[q * 4] = f.x; v[q * 4 + 1] = f.y; v[q * 4 + 2] = f.z; v[q * 4 + 3] = f.w;
    }
    v[16] = (t0 + 16 < 4096) ? xr[t0 + 16] : 0.f;
    unsigned int spk[8], zpk[8];
    float sum = 0.f;
#pragma unroll
    for (int q = 0; q < 8; ++q) {
      unsigned short s0 = f2bf(v[2 * q + 1]);
      unsigned short s1 = f2bf(v[2 * q + 2]);
      sum += bf2f(s0);
      sum += bf2f(s1);
      spk[q] = (unsigned int)s0 | ((unsigned int)s1 << 16);
      unsigned short z0 = (t0 == 0 && q == 0) ? (unsigned short)0 : f2bf(v[2 * q]);
      unsigned short z1 = f2bf(v[2 * q + 1]);
      zpk[q] = (unsigned int)z0 | ((unsigned int)z1 << 16);
    }
    *(uint4*)(xs + r * 4096 + t0)     = *(uint4*)(spk);
    *(uint4*)(xs + r * 4096 + t0 + 8) = *(uint4*)(spk + 4);
    *(uint4*)(xz + r * 4096 + t0)     = *(uint4*)(zpk);
    *(uint4*)(xz + r * 4096 + t0 + 8) = *(uint4*)(zpk + 4);
#pragma unroll
    for (int off = 32; off > 0; off >>= 1) sum += __shfl_down(sum, off);
    if ((tid & 63) == 0) red[tid >> 6] = sum;
    __syncthreads();
    if (tid == 0) rs[r] = red[0] + red[1] + red[2] + red[3];
  }
}

// Unified GEMM core, glds(16B) staging, XOR-swizzled unpadded LDS (rswz).
// C[r,n] = act(biasv[n] + sum_k Ae[base(r)+kOff+k] * Bt[((n)&bRowMask)*Ktot + bOffB + kOff + k])
// base(r) = (r + (r/RPB)*EXTRA) * BSCALE;  Ae = (nHalf && n0>=nHalf) ? A2 : A.
// SPLITK: bz picks k-chunk; partial -> outp/outp2 (bf16).
// NREG>0: NREG-region counted-vmcnt pipeline (T4): depth-(NREG-2) prefetch ahead,
//   raw s_barrier, vmcnt((NREG-2)*(AI+BI)) — loads stay in flight across barriers.
// NREG==0: BK=32*NH, stage-all -> barrier -> compute-all (1-phase).
// TRANS: out[bb*outBatchStride + (n0+f)*outLd + t_local] (bf16 via 2-pass LDS repack).
// ROWPACK: row-major bf16 store via LDS repack (stride BN+8), 2-pass when BM>64.
template<int BM, int BN, bool RELU, bool OBF16, bool TRANS, bool SPLITK, int NH,
         bool ROWPACK, int NREG>
__device__ __forceinline__ void gemm_core(
    int bx, int by, int bz, int nzTot, unsigned short* smem,
    const unsigned short* __restrict__ A,
    const unsigned short* __restrict__ A2,
    const unsigned short* __restrict__ Bt,
    const float* __restrict__ biasv,
    void* __restrict__ outp,
    void* __restrict__ outp2,
    int M, int Kchunk, int RPB, int EXTRA, int BSCALE,
    int nHalf, int bRowMask,
    long long bStrideB, long long outBatchStride, int outLd)
{
  constexpr int WM = BM / 2, WN = BN / 2;
  constexpr int NI = WM / 16, NJ = WN / 16;
  constexpr int AI = BM / 64;                 // glds instrs per wave per 32-chunk
  constexpr int BI = BN / 64;
  constexpr int SA1 = BM * 32, SB1 = BN * 32; // one 32-chunk region (shorts)
  unsigned short* sB0 = smem + (NREG > 0 ? 1 : NH) * SA1;

  const int tid  = threadIdx.x;
  const int lane = tid & 63;
  const int wave = tid >> 6;
  const int wm = wave >> 1, wn = wave & 1;
  const int lr = lane & 15, quad = lane >> 4;

  const int r0 = bx * BM;
  const int n0 = by * BN;
  const int bb = r0 / RPB;
  const int Ktot = SPLITK ? Kchunk * nzTot : Kchunk;
  const int kOff = SPLITK ? bz * Kchunk : 0;
  const long long bOffB = (long long)bb * bStrideB;
  const unsigned short* Ae = (nHalf && n0 >= nHalf) ? A2 : A;

  const int srow = lane >> 2;
  const int sg = (lane & 3) ^ rswz(srow);     // XOR swizzle on fetch side
  const unsigned short* gA[AI];
#pragma unroll
  for (int c = 0; c < AI; ++c) {
    int instr = c * 4 + wave;
    int row = instr * 16 + srow;
    int r = r0 + row; if (r > M - 1) r = M - 1;          // clamp partial tiles
    gA[c] = Ae + ((long long)r + (long long)(r / RPB) * EXTRA) * BSCALE + kOff + sg * 8;
  }
  const unsigned short* gB[BI];
#pragma unroll
  for (int c = 0; c < BI; ++c) {
    int instr = c * 4 + wave;
    int row = instr * 16 + srow;
    gB[c] = Bt + (long long)((n0 + row) & bRowMask) * Ktot + bOffB + kOff + sg * 8;
  }

  int aoff[NI], boff[NJ];
#pragma unroll
  for (int i = 0; i < NI; ++i) {
    int rr = wm * WM + i * 16 + lr;
    aoff[i] = rr * 32 + ((quad ^ rswz(rr)) * 8);
  }
#pragma unroll
  for (int j = 0; j < NJ; ++j) {
    int rr = wn * WN + j * 16 + lr;
    boff[j] = rr * 32 + ((quad ^ rswz(rr)) * 8);
  }

  float4v acc[NI][NJ];
  const float4v z4 = {0.f, 0.f, 0.f, 0.f};
#pragma unroll
  for (int i = 0; i < NI; ++i)
#pragma unroll
    for (int j = 0; j < NJ; ++j) acc[i][j] = z4;

  if constexpr (NREG > 0) {
    // NREG-region pipeline: region m holds one 32-chunk (A at +0, B at +SA1).
    constexpr int RS = SA1 + SB1;
    const int NT = Kchunk >> 5;
    auto stg = [&](int t, int m) {
      unsigned short* rb = smem + m * RS;
      int kk = t * 32;
#pragma unroll
      for (int c = 0; c < AI; ++c)
        __builtin_amdgcn_global_load_lds((gu32*)(gA[c] + kk),
                                         (lu32*)(rb + (c * 4 + wave) * 512), 16, 0, 0);
#pragma unroll
      for (int c = 0; c < BI; ++c)
        __builtin_amdgcn_global_load_lds((gu32*)(gB[c] + kk),
                                         (lu32*)(rb + SA1 + (c * 4 + wave) * 512), 16, 0, 0);
    };
#pragma unroll
    for (int i = 0; i < NREG - 1; ++i) if (i < NT) stg(i, i);
    int m = 0;
    for (int t = 0; t < NT; ++t) {
      if (NREG == 4 && t + 3 <= NT) vmwait<2 * (AI + BI)>();
      else if (t + 2 <= NT)         vmwait<AI + BI>();
      else                          vmwait<0>();
      __builtin_amdgcn_s_barrier();
      __builtin_amdgcn_sched_barrier(0);     // no ds_read may hoist above barrier
      int m2 = m + NREG - 1; if (m2 >= NREG) m2 -= NREG;
      if (t + NREG - 1 < NT) stg(t + NREG - 1, m2);
      const unsigned short* rb = smem + m * RS;
      short8 af[NI], bfr[NJ];
#pragma unroll
      for (int i = 0; i < NI; ++i) af[i] = *(const short8*)(rb + aoff[i]);
#pragma unroll
      for (int j = 0; j < NJ; ++j) bfr[j] = *(const short8*)(rb + SA1 + boff[j]);
#pragma unroll
      for (int i = 0; i < NI; ++i)
#pragma unroll
        for (int j = 0; j < NJ; ++j)
          acc[i][j] = __builtin_amdgcn_mfma_f32_16x16x32_bf16(af[i], bfr[j], acc[i][j], 0, 0, 0);
      if (++m == NREG) m = 0;
    }
    __syncthreads();                         // all reads done before epilogue reuses LDS
  } else {
    for (int k0 = 0; k0 < Kchunk; k0 += 32 * NH) {
#pragma unroll
      for (int h = 0; h < NH; ++h) {
#pragma unroll
        for (int c = 0; c < AI; ++c)
          __builtin_amdgcn_global_load_lds((gu32*)(gA[c] + k0 + h * 32),
                                           (lu32*)(smem + (c * 4 + wave) * 512 + h * SA1), 16, 0, 0);
#pragma unroll
        for (int c = 0; c < BI; ++c)
          __builtin_amdgcn_global_load_lds((gu32*)(gB[c] + k0 + h * 32),
                                           (lu32*)(sB0 + (c * 4 + wave) * 512 + h * SB1), 16, 0, 0);
      }
      __syncthreads();
#pragma unroll
      for (int h = 0; h < NH; ++h) {
        short8 af[NI], bfr[NJ];
#pragma unroll
        for (int i = 0; i < NI; ++i) af[i] = *(const short8*)(smem + h * SA1 + aoff[i]);
#pragma unroll
        for (int j = 0; j < NJ; ++j) bfr[j] = *(const short8*)(sB0 + h * SB1 + boff[j]);
#pragma unroll
        for (int i = 0; i < NI; ++i)
#pragma unroll
          for (int j = 0; j < NJ; ++j)
            acc[i][j] = __builtin_amdgcn_mfma_f32_16x16x32_bf16(af[i], bfr[j], acc[i][j], 0, 0, 0);
      }
      __syncthreads();
    }
  }

  if (TRANS) {
    // 2-pass repack: pass p handles f-rows [p*WN, p*WN+WN) in a [WN][BM+8] buffer.
    unsigned short* Ts = smem;
    const int t0l = r0 - bb * RPB;
#pragma unroll
    for (int p = 0; p < 2; ++p) {
      if (wn == p) {
#pragma unroll
        for (int j = 0; j < NJ; ++j) {
          int frl = j * 16 + lr;                     // local f row in [0,WN)
          float bv = biasv[n0 + p * WN + frl];
#pragma unroll
          for (int i = 0; i < NI; ++i) {
            int tr = wm * WM + i * 16 + quad * 4;
            unsigned long long pk = 0;
#pragma unroll
            for (int g = 0; g < 4; ++g) {
              float vv = acc[i][j][g] + bv;
              if (RELU) vv = fmaxf(vv, 0.f);
              pk |= (unsigned long long)f2bf(vv) << (16 * g);
            }
            *(unsigned long long*)(Ts + frl * (BM + 8) + tr) = pk;
          }
        }
      }
      __syncthreads();
      // 256 threads store WN=64 rows x BM elements: 4 threads/row, BM/4 elems each
      int frl = tid >> 2, sgg = tid & 3;
      unsigned short* dst = (unsigned short*)outp + (long long)bb * outBatchStride
                          + (long long)(n0 + p * WN + frl) * outLd + t0l + sgg * (BM / 4);
      const unsigned short* srcp = Ts + frl * (BM + 8) + sgg * (BM / 4);
#pragma unroll
      for (int u = 0; u < BM / 32; ++u)
        *(uint4*)(dst + u * 8) = *(const uint4*)(srcp + u * 8);
      __syncthreads();
    }
  } else if (ROWPACK) {
    // row-major bf16 store via LDS repack (stride BN+8) + dwordx4.
    // 2-pass over row-halves when BM>64 so the buffer fits under the stage LDS.
    constexpr int P  = (BM > 64) ? 2 : 1;
    constexpr int RP = BM / P;                // rows per pass
    constexpr int BNP = BN + 8;
    constexpr int TPR = 256 / RP;             // threads per output row
    constexpr int EPT = BN / TPR;             // elements per thread
    void* op = (SPLITK && bz) ? outp2 : outp;
    unsigned short* R = smem;
#pragma unroll
    for (int p = 0; p < P; ++p) {
      if (P == 1 || wm == p) {
#pragma unroll
        for (int j = 0; j < NJ; ++j) {
          int cc = wn * WN + j * 16 + lr;
#pragma unroll
          for (int i = 0; i < NI; ++i) {
            int rl = (P == 1 ? wm * WM : 0) + i * 16 + quad * 4;
#pragma unroll
            for (int g = 0; g < 4; ++g)
              R[(rl + g) * BNP + cc] = f2bf(acc[i][j][g]);
          }
        }
      }
      __syncthreads();
      int rloc = tid / TPR, part = tid % TPR;
      unsigned short* dstp = (unsigned short*)op
                           + (long long)(r0 + p * RP + rloc) * outLd + n0 + part * EPT;
      const unsigned short* srcp = R + rloc * BNP + part * EPT;
#pragma unroll
      for (int u = 0; u < EPT / 8; ++u)
        *(uint4*)(dstp + u * 8) = *(const uint4*)(srcp + u * 8);
      if (p + 1 < P) __syncthreads();
    }
  } else {
    void* op = (SPLITK && bz) ? outp2 : outp;
#pragma unroll
    for (int j = 0; j < NJ; ++j) {
      int n_g = n0 + wn * WN + j * 16 + lr;
      float bv = biasv ? biasv[n_g] : 0.f;
#pragma unroll
      for (int i = 0; i < NI; ++i) {
        int r_base = r0 + wm * WM + i * 16 + quad * 4;
#pragma unroll
        for (int g = 0; g < 4; ++g) {
          int r_g = r_base + g;
          if (r_g >= M) continue;
          float v = acc[i][j][g] + bv;
          if (RELU) v = fmaxf(v, 0.f);
          long long oidx = (long long)r_g * outLd + n_g;
          if (OBF16) ((unsigned short*)op)[oidx] = f2bf(v);
          else       ((float*)op)[oidx] = v;
        }
      }
    }
  }
}

// Standalone GEMM wrapper (used for G).
// REMAP: flat 1D launch; bx = (lin&7)*4 + ((lin>>3)&3) pins one BATCH per XCD:
//   its 4 MB h1T panel lives in that XCD's L2, and all 4 by-consumers of each
//   A chunk share the same L2 (FETCH 165 -> 49 MB, R5).
template<int BM, int BN, bool RELU, bool OBF16, bool TRANS, bool SPLITK, int NH,
         bool ROWPACK, int NREG, bool REMAP>
__global__ __launch_bounds__(256)
void gemm_bt(const unsigned short* __restrict__ A,
             const unsigned short* __restrict__ A2,
             const unsigned short* __restrict__ Bt,
             const float* __restrict__ biasv,
             void* __restrict__ outp,
             void* __restrict__ outp2,
             int M, int Kchunk, int RPB, int EXTRA, int BSCALE,
             int nHalf, int bRowMask,
             long long bStrideB, long long outBatchStride, int outLd)
{
  constexpr int STAGE = (NREG > 0 ? NREG : NH) * (BM * 32 + BN * 32);
  constexpr int REPK = TRANS ? (BN / 2) * (BM + 8)
                     : (ROWPACK ? (BM > 64 ? (BM / 2) * (BN + 8) : BM * (BN + 8)) : 0);
  constexpr int SMEMN = (REPK > STAGE) ? REPK : STAGE;
  __shared__ unsigned short smem[SMEMN];
  int bx, by, bz, nz;
  if (REMAP) {
    int lin = blockIdx.x;
    bx = (lin & 7) * 4 + ((lin >> 3) & 3);   // batch bb = bx/4 = XCD id
    by = (lin >> 5) & 7;
    bz = lin >> 8;
    nz = 2;
  } else {
    bx = blockIdx.x; by = blockIdx.y; bz = blockIdx.z; nz = gridDim.z;
  }
  gemm_core<BM, BN, RELU, OBF16, TRANS, SPLITK, NH, ROWPACK, NREG>(
      bx, by, bz, nz, smem,
      A, A2, Bt, biasv, outp, outp2,
      M, Kchunk, RPB, EXTRA, BSCALE, nHalf, bRowMask,
      bStrideB, outBatchStride, outLd);
}

// conv1: blocks [0,1024) conv1-w (TRANS 128x128), [1024,1284) conv1-b (64x128).
// 3-region counted-vmcnt pipelined (48 KB LDS -> 3 blocks/CU).
__global__ __launch_bounds__(256) void conv1(
    const unsigned short* __restrict__ zb,
    const unsigned short* __restrict__ w1T,
    const unsigned short* __restrict__ b1T,
    const float* __restrict__ wb1,
    const float* __restrict__ bb1,
    unsigned short* __restrict__ h1T,
    unsigned short* __restrict__ h1b)
{
  __shared__ unsigned short smem[24576];   // 3 regions x (128+128)*32 shorts
  int g = blockIdx.x;
  if (g < 1024) {
    // conv1-w -> h1T (TRANS, relu): M=8*4096, K=256, A row=(r+2bb)*128
    gemm_core<128, 128, true, true, true, false, 1, false, 3>(
        g & 255, g >> 8, 0, 1, smem,
        zb, nullptr, w1T, wb1, h1T, nullptr,
        32768, 256, 4096, 2, 128, 0, 0xFFFF, 0, 512ll * 4096, 4096);
  } else {
    int idx = g - 1024;
    // conv1-b (t<513): M=8*513, A row=(r+3585bb)*128 -> h1b bf16
    gemm_core<64, 128, true, true, false, false, 1, false, 3>(
        idx % 65, idx / 65, 0, 1, smem,
        zb, nullptr, b1T, bb1, h1b, nullptr,
        4104, 256, 513, 3585, 128, 0, 0xFFFF, 0, 0, 512);
  }
}

// Fused final, 3 K-segments (K=3072):
//   k in [0,1024):    A=p0[r,k],                 B=w2T[n,k]
//   k in [1024,2048): A=p1[r,k-1024],            B=w2T[n,k-1024]
//   k in [2048,3072): A=h1b[(r+r/512)*512+k'],   B=b2T[n,k']     (k'=k-2048)
// out[r,n] = acc + rs[r]*wb2[n] + bb2[n].  BM=BN=64, glds staging.
// 4-region counted-vmcnt pipeline: region = one 64-k chunk (A0,A1,B0,B1),
// depth-2-ahead prefetch, vmcnt(8)/raw-barrier.
__global__ __launch_bounds__(256) void final_gemm3(
    const unsigned short* __restrict__ p0,
    const unsigned short* __restrict__ p1,
    const unsigned short* __restrict__ h1b,
    const unsigned short* __restrict__ w2T,
    const unsigned short* __restrict__ b2T,
    const float* __restrict__ rs,
    const float* __restrict__ wb2,
    const float* __restrict__ bb2,
    float* __restrict__ out)
{
  constexpr int RS = 8192;                 // shorts: A0|A1|B0|B1 (2048 each)
  __shared__ unsigned short smem[4 * RS];  // 64 KB, 2 blocks/CU
  const int tid = threadIdx.x;
  const int lane = tid & 63, wave = tid >> 6;
  const int wm = wave >> 1, wn = wave & 1;
  const int lr = lane & 15, quad = lane >> 4;
  const int r0 = blockIdx.x * 64, n0 = blockIdx.y * 64;

  const int srow = lane >> 2;
  const int sg = (lane & 3) ^ rswz(srow);
  const int row = wave * 16 + srow;
  const int rA = r0 + row;
  const int rB = n0 + row;
  const unsigned short* aP[3] = {
    p0 + (long long)rA * 1024 + sg * 8,
    p1 + (long long)rA * 1024 + sg * 8,
    h1b + ((long long)rA + (rA >> 9)) * 512 + sg * 8 };
  const unsigned short* bP[3] = {
    w2T + (long long)rB * 1024 + sg * 8,
    w2T + (long long)rB * 1024 + sg * 8,
    b2T + (long long)rB * 1024 + sg * 8 };

  int aoff[2], boff[2];
#pragma unroll
  for (int i = 0; i < 2; ++i) {
    int rr = wm * 32 + i * 16 + lr;
    aoff[i] = rr * 32 + ((quad ^ rswz(rr)) * 8);
    int nn = wn * 32 + i * 16 + lr;
    boff[i] = nn * 32 + ((quad ^ rswz(nn)) * 8);
  }

  float4v acc[2][2];
  const float4v z4 = {0.f, 0.f, 0.f, 0.f};
  acc[0][0] = z4; acc[0][1] = z4; acc[1][0] = z4; acc[1][1] = z4;

  const int wslot = wave * 512;
  auto stg = [&](int t, int m) {           // stage 64-k chunk t into region m
    int k = t * 64; int seg = k >> 10; int kk = k & 1023;
    unsigned short* base = smem + m * RS;
    __builtin_amdgcn_global_load_lds((gu32*)(aP[seg] + kk),      (lu32*)(base + wslot), 16, 0, 0);
    __builtin_amdgcn_global_load_lds((gu32*)(aP[seg] + kk + 32), (lu32*)(base + 2048 + wslot), 16, 0, 0);
    __builtin_amdgcn_global_load_lds((gu32*)(bP[seg] + kk),      (lu32*)(base + 4096 + wslot), 16, 0, 0);
    __builtin_amdgcn_global_load_lds((gu32*)(bP[seg] + kk + 32), (lu32*)(base + 6144 + wslot), 16, 0, 0);
  };
  stg(0, 0); stg(1, 1); stg(2, 2);
  int m = 0;
  for (int t = 0; t < 48; ++t) {
    if (t <= 45)      vmwait<8>();
    else if (t == 46) vmwait<4>();
    else              vmwait<0>();
    __builtin_amdgcn_s_barrier();
    __builtin_amdgcn_sched_barrier(0);
    int m2 = m + 3; if (m2 >= 4) m2 -= 4;
    if (t + 3 < 48) stg(t + 3, m2);
    const unsigned short* base = smem + m * RS;
#pragma unroll
    for (int h = 0; h < 2; ++h) {
      short8 af[2], bfr[2];
      af[0] = *(const short8*)(base + h * 2048 + aoff[0]);
      af[1] = *(const short8*)(base + h * 2048 + aoff[1]);
      bfr[0] = *(const short8*)(base + 4096 + h * 2048 + boff[0]);
      bfr[1] = *(const short8*)(base + 4096 + h * 2048 + boff[1]);
#pragma unroll
      for (int i = 0; i < 2; ++i)
#pragma unroll
        for (int j = 0; j < 2; ++j)
          acc[i][j] = __builtin_amdgcn_mfma_f32_16x16x32_bf16(af[i], bfr[j], acc[i][j], 0, 0, 0);
    }
    if (++m == 4) m = 0;
  }

#pragma unroll
  for (int j = 0; j < 2; ++j) {
    int n_g = n0 + wn * 32 + j * 16 + lr;
    float w2b = wb2[n_g], bbv = bb2[n_g];
#pragma unroll
    for (int i = 0; i < 2; ++i) {
      int rb2 = r0 + wm * 32 + i * 16 + quad * 4;
#pragma unroll
      for (int g = 0; g < 4; ++g) {
        int r_g = rb2 + g;
        out[(long long)r_g * 512 + n_g] = acc[i][j][g] + rs[r_g] * w2b + bbv;
      }
    }
  }
}

extern "C" void kernel_launch(void* const* d_in, const int* in_sizes, int n_in,
                              void* d_out, int out_size, void* d_ws, size_t ws_size,
                              hipStream_t stream) {
  const float* x   = (const float*)d_in[0];
  const float* z   = (const float*)d_in[1];
  const float* ww1 = (const float*)d_in[2];
  const float* wb1 = (const float*)d_in[3];
  const float* ww2 = (const float*)d_in[4];
  const float* wb2 = (const float*)d_in[5];
  const float* bw1 = (const float*)d_in[6];
  const float* bb1 = (const float*)d_in[7];
  const float* bw2 = (const float*)d_in[8];
  const float* bb2 = (const float*)d_in[9];

  char* ws = (char*)d_ws;
  unsigned short* xs  = (unsigned short*)ws; ws += 16777216ll * 2;  // (4096,4096) shifted bf16
  unsigned short* xz  = (unsigned short*)ws; ws += 16777216ll * 2;  // (4096,4096) t0-zeroed bf16
  unsigned short* zb  = (unsigned short*)ws; ws += 4196352ll  * 2;  // (8,4098,128) bf16; reused as p0
  unsigned short* h1T = (unsigned short*)ws; ws += 16777216ll * 2;  // (8,512,4096) h1 transposed bf16
  unsigned short* h1b = (unsigned short*)ws; ws += 2101248ll  * 2;  // (8,513,512) bias-path h1 bf16
  unsigned short* w2T = (unsigned short*)ws; ws += 524288ll * 2;    // (512,1024)
  unsigned short* b2T = (unsigned short*)ws; ws += 524288ll * 2;
  float* rs = (float*)ws;                    ws += 4096ll * 4;      // rowsum(xs)
  char* tail = ws;
  // w1T/b1T live until conv1 completes, then tail becomes p1
  unsigned short* w1T = (unsigned short*)tail;                      // (512,256)
  unsigned short* b1T = (unsigned short*)tail + 131072;             // (512,256)
  unsigned short* p0  = zb;                                         // (4096,1024) bf16 (zb dead by then)
  unsigned short* p1  = (unsigned short*)tail;                      // (4096,1024) bf16

  // 1) weights/z prep (LDS-tiled transposes) + x -> xs/xz + rowsum, one dispatch
  prep<<<5441, 256, 0, stream>>>(ww1, ww2, bw1, bw2, z, x,
                                 w1T, w2T, b1T, b2T, zb, xs, xz, rs);
  // 2) conv1-w + conv1-b, 3-region counted-vmcnt pipelined
  conv1<<<1284, 256, 0, stream>>>(zb, w1T, b1T, wb1, bb1, h1T, h1b);
  // 3) G = [xs ; xz] @ h1T^T, 128x128 tiles, 4-region depth-3 pipeline,
  //    split-K x2 -> p0,p1 (bf16, ROWPACK): M=4096, N=1024, Kchunk=2048.
  //    Flat 512-block launch, batch-per-XCD remap.
  gemm_bt<128, 128, false, true, false, true, 1, true, 4, true><<<512, 256, 0, stream>>>(
      xs, xz, h1T, nullptr, p0, p1,
      4096, 2048, 512, 0, 4096, 512, 511, 512ll * 4096, 0, 1024);
  // 4) out = p0@w2 + p1@w2 + h1b-pair@b2 + rs x wb2 + bb2  (K=3072, 4-region pipe)
  final_gemm3<<<dim3(64, 8), 256, 0, stream>>>(
      p0, p1, h1b, w2T, b2T, rs, wb2, bb2, (float*)d_out);
}